// Round 2
// baseline (727.287 us; speedup 1.0000x reference)
//
#include <hip/hip_runtime.h>
#include <math.h>

// Problem constants
#define B_ 32
#define T_ 4096
#define QD_ 1024
#define MD_ 512
#define AD_ 128
#define F_ 32
#define K_ 31
#define PAD_ 15

#define TT 128                // timesteps per score block (4-wave block)
#define NBLK (T_ / TT)        // 32 t-blocks per batch

typedef float f32x16 __attribute__((ext_vector_type(16)));
typedef unsigned int uint4v __attribute__((ext_vector_type(4)));

// round-half-up float->bf16 pair packed in one VGPR via v_perm
__device__ inline unsigned pk_bf2(float lo, float hi) {
    unsigned ul = __float_as_uint(lo) + 0x8000u;
    unsigned uh = __float_as_uint(hi) + 0x8000u;
    return __builtin_amdgcn_perm(uh, ul, 0x07060302u);
}

__device__ inline unsigned short f2bf_rn(float f) {
    unsigned u = __float_as_uint(f);
    u += 0x7fffu + ((u >> 16) & 1u);
    return (unsigned short)(u >> 16);
}

__device__ inline float bf2f(unsigned short u) {
    return __uint_as_float(((unsigned)u) << 16);
}

// v_mfma via inline asm. s_nop 1 covers VALU-write -> MFMA-read hazard.
__device__ inline void mfma32(f32x16& c, uint4v a, uint4v b) {
    asm("s_nop 1\n\tv_mfma_f32_32x32x16_bf16 %0, %1, %2, %0"
        : "+v"(c) : "v"(a), "v"(b));
}

// async global -> LDS, 16B per lane. LDS dst is WAVE-UNIFORM base (+lane*16 in HW).
__device__ inline void gload_lds16(const float* g, void* lds) {
    __builtin_amdgcn_global_load_lds(
        (const __attribute__((address_space(1))) void*)g,
        (__attribute__((address_space(3))) void*)lds, 16, 0, 0);
}

// ---------------- Kernel A: Wm swizzle + pq partials + counter zero ---------
// bx<32 : wmT_sw[((kk*4+ct)*64+lane)*8+j] = bf16(Wm[kk*16+(lane>>5)*8+j][ct*32+(lane&31)])
// bx>=32: pqp[qc][b][a] = sum_{i in qc-chunk} query[b][i]*Wq[i][a]   (no atomics)
__global__ __launch_bounds__(256) void k_pre(
    const float* __restrict__ Wm, unsigned short* __restrict__ wmT_sw,
    const float* __restrict__ query, const float* __restrict__ Wq,
    float* __restrict__ pqp, int* __restrict__ cnt) {
    __shared__ float s_t[128];
    const int bx = blockIdx.x;
    const int tid = threadIdx.x;
    if (bx < 32) {
        int gid = bx * 256 + tid;   // 0..8191
        int kk = gid >> 8;
        int ct = (gid >> 6) & 3;
        int lane = gid & 63;
        int k0 = kk * 16 + (lane >> 5) * 8;
        int a = ct * 32 + (lane & 31);
        unsigned short o[8];
#pragma unroll
        for (int j = 0; j < 8; j++) o[j] = f2bf_rn(Wm[(k0 + j) * AD_ + a]);
        uint4v v;
        v[0] = ((unsigned)o[1] << 16) | o[0];
        v[1] = ((unsigned)o[3] << 16) | o[2];
        v[2] = ((unsigned)o[5] << 16) | o[4];
        v[3] = ((unsigned)o[7] << 16) | o[6];
        *(uint4v*)(wmT_sw + (long)gid * 8) = v;
        if (bx == 0 && tid < B_) cnt[tid] = 0;
        return;
    }
    // pq partial
    const int pb = bx - 32;            // 0..255
    const int b = pb >> 3, qc = pb & 7;
    const int a = tid & 127, hf = tid >> 7;
    const float* qrow = query + b * QD_ + qc * 128 + hf * 64;
    const float* wq = Wq + (qc * 128 + hf * 64) * AD_ + a;
    float acc = 0.f;
#pragma unroll 4
    for (int i = 0; i < 64; i++) acc += qrow[i] * wq[i * AD_];
    if (hf) s_t[a] = acc;
    __syncthreads();
    if (!hf) pqp[((long)qc * B_ + b) * AD_ + a] = acc + s_t[a];
}

// ---------------- Kernel B: conv + loc@Wl + all biases -> ploc (bf16) -------
__global__ __launch_bounds__(256) void k_ploc(
    const float* __restrict__ alignments, const float* __restrict__ convw,
    const float* __restrict__ convb, const float* __restrict__ Wl,
    const float* __restrict__ bl, const float* __restrict__ bm,
    const float* __restrict__ bq, const float* __restrict__ pqp,
    unsigned short* __restrict__ ploc) {
    __shared__ float s_cw[F_ * 2 * K_];
    __shared__ float s_al[(128 + K_ - 1) * 2];
    __shared__ float s_loc[128 * F_];

    const int tid = threadIdx.x;
    const int b = blockIdx.y;
    const int t0 = blockIdx.x * 128;

    for (int i = tid; i < F_ * 2 * K_; i += 256) s_cw[i] = convw[i];
    for (int i = tid; i < (128 + K_ - 1) * 2; i += 256) {
        int tg = t0 + (i >> 1) - PAD_;
        s_al[i] = (tg >= 0 && tg < T_) ? alignments[((long)b * T_ + tg) * 2 + (i & 1)] : 0.f;
    }
    __syncthreads();

    for (int i = tid; i < 128 * F_; i += 256) {
        int f = i & (F_ - 1);
        int t = i >> 5;
        float acc = convb[f];
        const float* w0 = &s_cw[f * (2 * K_)];
        const float* w1 = w0 + K_;
        const float2* ap = (const float2*)&s_al[t * 2];
#pragma unroll
        for (int k = 0; k < K_; k++) {
            float2 a2 = ap[k];
            acc += a2.x * w0[k] + a2.y * w1[k];
        }
        s_loc[t * F_ + f] = acc;
    }
    __syncthreads();

    const int a = tid & 127;
    float wl[F_];
#pragma unroll
    for (int f = 0; f < F_; f++) wl[f] = Wl[f * AD_ + a];
    float pqv = 0.f;
#pragma unroll
    for (int q = 0; q < 8; q++) pqv += pqp[((long)q * B_ + b) * AD_ + a];
    const float base = pqv + bq[a] + bm[a] + bl[a];
    unsigned short* outp = ploc + ((long)b * T_ + t0) * AD_ + a;
    for (int t = (tid >> 7); t < 128; t += 2) {
        float acc = base;
        const float* lr = &s_loc[t * F_];
#pragma unroll
        for (int f = 0; f < F_; f++) acc += lr[f] * wl[f];
        outp[(long)t * AD_] = f2bf_rn(acc);
    }
}

// ---------------- Kernel C: m97-style MFMA score + context + finalize -------
// 4 waves, BM=128 (t), BN=128 (a), BK=32 f32 chunks. A staged into LDS via
// global_load_lds (source-side XOR swizzle at 16B granularity, LDS linear).
// Wave w owns rows w*32..w*32+31, all 128 cols. B read from L2-resident wmT_sw.
__global__ __launch_bounds__(256) void k_score_ctx(
    const float* __restrict__ memory, const unsigned char* __restrict__ mask,
    const unsigned short* __restrict__ wmT_sw, const unsigned short* __restrict__ ploc,
    const float* __restrict__ vw, const float* __restrict__ vb,
    float* __restrict__ bmax, float* __restrict__ bden,
    float* __restrict__ num, float* __restrict__ oalign,
    float* __restrict__ ctx, int* __restrict__ cnt) {
    __shared__ __align__(16) float sA[2][128 * 32];   // 32 KB double buffer
    __shared__ float s_sc[TT];
    __shared__ float s_w[TT];
    __shared__ float s_red[8];
    __shared__ float f_m[NBLK], f_f[NBLK];
    __shared__ float f_Ds;
    __shared__ int s_last;

    const int tid = threadIdx.x;
    const int w = tid >> 6;
    const int lane = tid & 63;
    const int l31 = lane & 31;
    const int h = lane >> 5;
    const int b = blockIdx.y;
    const int blk = blockIdx.x;
    const int t0 = blk * TT;

    const float* aptr = memory + ((long)b * T_ + t0) * MD_;

    // --- staging addresses: instr j covers rows (j*4+w)*8 + (lane>>3) ---
    const int srow = lane >> 3;                 // 0..7
    const int sc16 = (lane & 7) ^ srow;         // source-side swizzled 16B chunk
    const float* gA[4];
#pragma unroll
    for (int j = 0; j < 4; j++)
        gA[j] = aptr + (long)((j * 4 + w) * 8 + srow) * MD_ + sc16 * 4;

    // --- LDS fragment read offsets (swizzled), loop-invariant ---
    const int Rl = w * 32 + l31;
    const int rx = Rl & 7;
    const int o_a0 = (Rl * 8 + ((2 * h) ^ rx)) * 16;
    const int o_a1 = (Rl * 8 + ((2 * h + 1) ^ rx)) * 16;
    const int o_b0 = (Rl * 8 + ((4 + 2 * h) ^ rx)) * 16;
    const int o_b1 = (Rl * 8 + ((5 + 2 * h) ^ rx)) * 16;

    const unsigned short* bpk = wmT_sw + lane * 8;

    f32x16 c0, c1, c2, c3;
#pragma unroll
    for (int i = 0; i < 16; i++) { c0[i] = 0.f; c1[i] = 0.f; c2[i] = 0.f; c3[i] = 0.f; }

    // prologue: stage chunk 0 into buf 0
#pragma unroll
    for (int j = 0; j < 4; j++)
        gload_lds16(gA[j], (char*)(&sA[0][0]) + (j * 4 + w) * 1024);
    __syncthreads();

#pragma unroll 2
    for (int c = 0; c < 16; ++c) {
        const int cb = c & 1;
        if (c < 15) {
#pragma unroll
            for (int j = 0; j < 4; j++)
                gload_lds16(gA[j] + (c + 1) * 32,
                            (char*)(&sA[cb ^ 1][0]) + (j * 4 + w) * 1024);
        }
        const unsigned short* bc = bpk + (c << 12);
        uint4v b00 = *(const uint4v*)(bc);
        uint4v b01 = *(const uint4v*)(bc + 512);
        uint4v b02 = *(const uint4v*)(bc + 1024);
        uint4v b03 = *(const uint4v*)(bc + 1536);
        uint4v b10 = *(const uint4v*)(bc + 2048);
        uint4v b11 = *(const uint4v*)(bc + 2560);
        uint4v b12 = *(const uint4v*)(bc + 3072);
        uint4v b13 = *(const uint4v*)(bc + 3584);
        const char* ab = (const char*)(&sA[cb][0]);
        float4 q0 = *(const float4*)(ab + o_a0);
        float4 q1 = *(const float4*)(ab + o_a1);
        float4 q2 = *(const float4*)(ab + o_b0);
        float4 q3 = *(const float4*)(ab + o_b1);
        uint4v af0, af1;
        af0[0] = pk_bf2(q0.x, q0.y); af0[1] = pk_bf2(q0.z, q0.w);
        af0[2] = pk_bf2(q1.x, q1.y); af0[3] = pk_bf2(q1.z, q1.w);
        af1[0] = pk_bf2(q2.x, q2.y); af1[1] = pk_bf2(q2.z, q2.w);
        af1[2] = pk_bf2(q3.x, q3.y); af1[3] = pk_bf2(q3.z, q3.w);
        mfma32(c0, af0, b00); mfma32(c1, af0, b01);
        mfma32(c2, af0, b02); mfma32(c3, af0, b03);
        mfma32(c0, af1, b10); mfma32(c1, af1, b11);
        mfma32(c2, af1, b12); mfma32(c3, af1, b13);
        __syncthreads();
    }
    asm volatile("s_nop 7\n\ts_nop 7\n\ts_nop 7" ::: "memory");

    // --- epilogue: tanh, dot with v, reduce over a ---
    const unsigned short* plp = ploc + ((long)b * T_ + t0 + w * 32) * AD_ + l31;
    const float vw0 = vw[l31];
    const float vw1 = vw[32 + l31];
    const float vw2 = vw[64 + l31];
    const float vw3 = vw[96 + l31];
#pragma unroll
    for (int i = 0; i < 16; i++) {
        const int crow = (i & 3) + 8 * (i >> 2) + 4 * h;
        const unsigned short* pr = plp + crow * AD_;
        float s = tanhf(c0[i] + bf2f(pr[0]))  * vw0
                + tanhf(c1[i] + bf2f(pr[32])) * vw1
                + tanhf(c2[i] + bf2f(pr[64])) * vw2
                + tanhf(c3[i] + bf2f(pr[96])) * vw3;
        s += __shfl_xor(s, 1);
        s += __shfl_xor(s, 2);
        s += __shfl_xor(s, 4);
        s += __shfl_xor(s, 8);
        s += __shfl_xor(s, 16);
        if (l31 == 0) s_sc[w * 32 + crow] = s;
    }
    __syncthreads();

    // --- local softmax stats over 128 rows ---
    float sv = -INFINITY;
    if (tid < TT) {
        sv = s_sc[tid] + vb[0];
        if (mask[(long)b * T_ + t0 + tid]) sv = -INFINITY;
    }
    float m = sv;
#pragma unroll
    for (int off = 32; off >= 1; off >>= 1) m = fmaxf(m, __shfl_xor(m, off));
    if (lane == 0) s_red[w] = m;
    __syncthreads();
    m = fmaxf(fmaxf(s_red[0], s_red[1]), fmaxf(s_red[2], s_red[3]));
    float e = 0.f;
    if (tid < TT) {
        e = (sv == -INFINITY) ? 0.f : expf(sv - m);
        s_w[tid] = e;
        oalign[(long)b * T_ + t0 + tid] = e;   // rescaled in finalize
    }
    float d = e;
    d += __shfl_xor(d, 1);
    d += __shfl_xor(d, 2);
    d += __shfl_xor(d, 4);
    d += __shfl_xor(d, 8);
    d += __shfl_xor(d, 16);
    d += __shfl_xor(d, 32);
    if (lane == 0) s_red[4 + w] = d;
    __syncthreads();
    if (tid == 0) {
        bmax[b * NBLK + blk] = m;
        bden[b * NBLK + blk] = s_red[4] + s_red[5] + s_red[6] + s_red[7];
    }

    // --- partial context: num[md] = sum_t e_t * mem[t][md] (tile L2/L3-hot) ---
    {
        const float2* mp = (const float2*)aptr + tid;   // md = 2*tid
        float ax = 0.f, ay = 0.f;
#pragma unroll 8
        for (int t = 0; t < TT; t++) {
            const float2 v = mp[t * 256];
            const float wt = s_w[t];
            ax += wt * v.x;
            ay += wt * v.y;
        }
        float2 o; o.x = ax; o.y = ay;
        *(float2*)(num + ((long)b * NBLK + blk) * MD_ + tid * 2) = o;
    }

    // --- last block of this batch combines partials (replaces k_reduce) ---
    __threadfence();
    __syncthreads();
    if (tid == 0) s_last = (atomicAdd(&cnt[b], 1) == NBLK - 1) ? 1 : 0;
    __syncthreads();
    if (!s_last) return;
    __threadfence();

    if (tid < NBLK) f_m[tid] = bmax[b * NBLK + tid];
    __syncthreads();
    float M = -INFINITY;
#pragma unroll
    for (int i = 0; i < NBLK; i++) M = fmaxf(M, f_m[i]);
    if (tid < NBLK) f_f[tid] = (f_m[tid] == -INFINITY) ? 0.f : expf(f_m[tid] - M);
    __syncthreads();
    if (tid == 0) {
        float D = 0.f;
        for (int i = 0; i < NBLK; i++) D += f_f[i] * bden[b * NBLK + i];
        f_Ds = D;
    }
    __syncthreads();
    const float invD = 1.f / f_Ds;

#pragma unroll
    for (int g = 0; g < 2; g++) {
        const int col = tid + g * 256;
        float acc = 0.f;
#pragma unroll 8
        for (int k2 = 0; k2 < NBLK; k2++)
            acc += f_f[k2] * num[((long)b * NBLK + k2) * MD_ + col];
        ctx[b * MD_ + col] = acc * invD;
    }
    for (int t = tid; t < T_; t += 256)
        oalign[(long)b * T_ + t] *= f_f[t >> 7] * invD;
}

extern "C" void kernel_launch(void* const* d_in, const int* in_sizes, int n_in,
                              void* d_out, int out_size, void* d_ws, size_t ws_size,
                              hipStream_t stream) {
    const float* query      = (const float*)d_in[0];
    const float* memory     = (const float*)d_in[1];
    const float* alignments = (const float*)d_in[2];
    const unsigned char* mask = (const unsigned char*)d_in[3];
    const float* Wq    = (const float*)d_in[4];
    const float* bq    = (const float*)d_in[5];
    const float* Wm    = (const float*)d_in[6];
    const float* bm    = (const float*)d_in[7];
    const float* convw = (const float*)d_in[8];
    const float* convb = (const float*)d_in[9];
    const float* Wl    = (const float*)d_in[10];
    const float* bl    = (const float*)d_in[11];
    const float* vw    = (const float*)d_in[12];
    const float* vb    = (const float*)d_in[13];

    float* out = (float*)d_out;
    float* ctx = out;                      // [B,MD]
    float* oalign = out + B_ * MD_;        // [B,T]

    // workspace layout (~34.5 MB):
    //   pqp    : 8*B*AD floats    (128 KB)
    //   bmax   : B*NBLK floats    (4 KB)
    //   bden   : B*NBLK floats    (4 KB)
    //   num    : B*NBLK*MD floats (2 MB)
    //   cnt    : B ints           (128 B)
    //   wmT_sw : 65536 ushorts    (128 KB)
    //   ploc   : B*T*AD ushorts   (32 MB)
    float* ws = (float*)d_ws;
    float* pqp  = ws;
    float* bmax = pqp + 8 * B_ * AD_;
    float* bden = bmax + B_ * NBLK;
    float* num  = bden + B_ * NBLK;
    int* cnt    = (int*)(num + (long)B_ * NBLK * MD_);
    unsigned short* wmT_sw = (unsigned short*)(cnt + B_);
    unsigned short* ploc   = wmT_sw + (long)65536;

    k_pre<<<288, 256, 0, stream>>>(Wm, wmT_sw, query, Wq, pqp, cnt);
    k_ploc<<<dim3(T_ / 128, B_), 256, 0, stream>>>(alignments, convw, convb, Wl, bl, bm, bq, pqp, ploc);
    k_score_ctx<<<dim3(NBLK, B_), 256, 0, stream>>>(
        memory, mask, wmT_sw, ploc, vw, vb, bmax, bden, num, oalign, ctx, cnt);
}